// Round 2
// baseline (120.120 us; speedup 1.0000x reference)
//
#include <hip/hip_runtime.h>

// crop_and_resize (RoIAlign-style bilinear), fp32, NHWC.
// feats: (8, 64, 64, 256) fp32; boxes: (4000, 4); box_ind: (4000,)
// out:   (4000, 7, 7, 256) fp32
//
// One wave (64 lanes) handles one output cell (box, iy, ix): lane l covers
// channels [4l, 4l+4) via 16B vectors. Grid-stride over cells.

#define H 64
#define W 64
#define C 256
#define CROP_HW 49  // 7*7

typedef float f32x4 __attribute__((ext_vector_type(4)));

__global__ __launch_bounds__(256) void crop_resize_kernel(
    const float* __restrict__ feats,
    const float* __restrict__ boxes,
    const int*   __restrict__ box_ind,
    float*       __restrict__ out,
    int n_boxes)
{
    const int lane   = threadIdx.x & 63;
    const int wave   = (blockIdx.x * blockDim.x + threadIdx.x) >> 6;
    const int nwaves = (gridDim.x * blockDim.x) >> 6;
    const int ncells = n_boxes * CROP_HW;

    const f32x4* __restrict__ f4 = reinterpret_cast<const f32x4*>(feats);
    f32x4*       __restrict__ o4 = reinterpret_cast<f32x4*>(out);

    for (int cell = wave; cell < ncells; cell += nwaves) {
        const int b  = cell / CROP_HW;
        const int r  = cell - b * CROP_HW;
        const int iy = r / 7;
        const int ix = r - iy * 7;

        // wave-uniform box params (L1-cached; redundant per-lane load is cheap)
        const float by1 = boxes[b * 4 + 0];
        const float bx1 = boxes[b * 4 + 1];
        const float by2 = boxes[b * 4 + 2];
        const float bx2 = boxes[b * 4 + 3];
        const int   img = box_ind[b];

        // match reference order: step = (hi-lo)*(extent-1)/(n-1); s = lo*(extent-1) + i*step
        const float stepy = (by2 - by1) * 63.0f / 6.0f;
        const float stepx = (bx2 - bx1) * 63.0f / 6.0f;
        const float ys = by1 * 63.0f + (float)iy * stepy;
        const float xs = bx1 * 63.0f + (float)ix * stepx;

        const float y0f = floorf(ys);
        const float x0f = floorf(xs);
        const float wy  = ys - y0f;
        const float wx  = xs - x0f;

        const int y0 = min(max((int)y0f, 0), H - 1);
        const int y1 = min(y0 + 1, H - 1);
        const int x0 = min(max((int)x0f, 0), W - 1);
        const int x1 = min(x0 + 1, W - 1);

        const bool valid = (ys >= 0.0f) && (ys <= (float)(H - 1)) &&
                           (xs >= 0.0f) && (xs <= (float)(W - 1));

        // float4-granular index: ((img*H + y)*W + x)*(C/4) + lane
        const int base = img * (H * W * (C / 4));
        const int i00  = base + (y0 * W + x0) * (C / 4) + lane;
        const int i01  = base + (y0 * W + x1) * (C / 4) + lane;
        const int i10  = base + (y1 * W + x0) * (C / 4) + lane;
        const int i11  = base + (y1 * W + x1) * (C / 4) + lane;

        const f32x4 v00 = f4[i00];
        const f32x4 v01 = f4[i01];
        const f32x4 v10 = f4[i10];
        const f32x4 v11 = f4[i11];

        const f32x4 top = v00 + (v01 - v00) * wx;
        const f32x4 bot = v10 + (v11 - v10) * wx;
        f32x4 res = top + (bot - top) * wy;

        if (!valid) {
            res = (f32x4)0.0f;
        }

        // streaming store: don't let the 200 MB output evict the 32 MiB feats
        // from L2/L3 (output is never re-read).
        __builtin_nontemporal_store(res, &o4[(size_t)cell * (C / 4) + lane]);
    }
}

extern "C" void kernel_launch(void* const* d_in, const int* in_sizes, int n_in,
                              void* d_out, int out_size, void* d_ws, size_t ws_size,
                              hipStream_t stream) {
    const float* feats   = (const float*)d_in[0];
    const float* boxes   = (const float*)d_in[1];
    const int*   box_ind = (const int*)d_in[2];
    float*       out     = (float*)d_out;

    const int n_boxes = in_sizes[1] / 4;

    // 2048 blocks x 256 threads = 8192 waves; ~24 cells each (196k cells total).
    dim3 grid(2048), block(256);
    crop_resize_kernel<<<grid, block, 0, stream>>>(feats, boxes, box_ind, out, n_boxes);
}

// Round 3
// 78.272 us; speedup vs baseline: 1.5347x; 1.5347x over previous
//
#include <hip/hip_runtime.h>

// crop_and_resize (RoIAlign-style bilinear), fp32, NHWC.
// feats: (8, 64, 64, 256) fp32 = 4 MiB/image; boxes: (4000,4); box_ind: (4000,)
// out:   (4000, 7, 7, 256) fp32
//
// XCD-locality scheme: one image is exactly 4 MiB = one XCD's L2. Kernel 1
// buckets boxes by image (stable, deterministic). Kernel 2 assigns image i to
// blocks with blockIdx.x % 8 == i (round-robin block->XCD heuristic), so each
// XCD's gathers stay within one L2-resident image.

#define H 64
#define W 64
#define C 256
#define CROP_HW 49  // 7*7
#define NIMG 8

typedef float f32x4 __attribute__((ext_vector_type(4)));

// ---- kernel 1: stable bucket of box indices by image --------------------
// single block, 8 waves; wave w compacts boxes with box_ind==w.
__global__ __launch_bounds__(512) void bucket_kernel(
    const int* __restrict__ box_ind,
    int* __restrict__ order,     // [n] box ids grouped by image (stable)
    int* __restrict__ offsets,   // [9] bucket offsets
    int n)
{
    const int wave = threadIdx.x >> 6;   // 0..7 == image id
    const int lane = threadIdx.x & 63;
    __shared__ int counts[NIMG];

    // pass 1: count boxes of my image
    int cnt = 0;
    for (int i = lane; i < n; i += 64)
        cnt += (box_ind[i] == wave);
    for (int off = 32; off; off >>= 1)
        cnt += __shfl_down(cnt, off);
    if (lane == 0) counts[wave] = cnt;
    __syncthreads();

    int start = 0;
    for (int i = 0; i < wave; ++i) start += counts[i];
    if (threadIdx.x == 0) {
        int acc = 0;
        for (int i = 0; i < NIMG; ++i) { offsets[i] = acc; acc += counts[i]; }
        offsets[NIMG] = acc;
    }

    // pass 2: stable ballot compaction
    int pos = start;
    for (int base = 0; base < n; base += 64) {
        const int i = base + lane;
        const bool m = (i < n) && (box_ind[i] == wave);
        const unsigned long long mask = __ballot(m);
        const int below = __popcll(mask & ((1ULL << lane) - 1ULL));
        if (m) order[pos + below] = i;
        pos += __popcll(mask);
    }
}

// ---- kernel 2: bilinear crop, image-partitioned by XCD -------------------
__global__ __launch_bounds__(256) void crop_resize_xcd(
    const float* __restrict__ feats,
    const float* __restrict__ boxes,
    const int*   __restrict__ order,
    const int*   __restrict__ offsets,
    float*       __restrict__ out)
{
    const int img  = blockIdx.x & 7;     // block->XCD round-robin heuristic
    const int slot = blockIdx.x >> 3;    // 0..(gridDim/8 - 1)
    const int lane = threadIdx.x & 63;
    const int wv   = threadIdx.x >> 6;   // 0..3

    const int start  = offsets[img];
    const int nb     = offsets[img + 1] - start;
    const int ncells = nb * CROP_HW;
    const int wave_local = slot * 4 + wv;
    const int stride     = (gridDim.x >> 3) * 4;

    const f32x4* __restrict__ f4 = reinterpret_cast<const f32x4*>(feats)
                                   + (size_t)img * (H * W * (C / 4));
    f32x4* __restrict__ o4 = reinterpret_cast<f32x4*>(out);

    for (int c = wave_local; c < ncells; c += stride) {
        const int bi = c / CROP_HW;
        const int r  = c - bi * CROP_HW;
        const int iy = r / 7;
        const int ix = r - iy * 7;
        const int b  = order[start + bi];

        const float by1 = boxes[b * 4 + 0];
        const float bx1 = boxes[b * 4 + 1];
        const float by2 = boxes[b * 4 + 2];
        const float bx2 = boxes[b * 4 + 3];

        // reference order: step = (hi-lo)*(extent-1)/(n-1); s = lo*(extent-1)+i*step
        const float stepy = (by2 - by1) * 63.0f / 6.0f;
        const float stepx = (bx2 - bx1) * 63.0f / 6.0f;
        const float ys = by1 * 63.0f + (float)iy * stepy;
        const float xs = bx1 * 63.0f + (float)ix * stepx;

        const float y0f = floorf(ys);
        const float x0f = floorf(xs);
        const float wy  = ys - y0f;
        const float wx  = xs - x0f;

        const int y0 = min(max((int)y0f, 0), H - 1);
        const int y1 = min(y0 + 1, H - 1);
        const int x0 = min(max((int)x0f, 0), W - 1);
        const int x1 = min(x0 + 1, W - 1);

        const bool valid = (ys >= 0.0f) && (ys <= (float)(H - 1)) &&
                           (xs >= 0.0f) && (xs <= (float)(W - 1));

        const int i00 = (y0 * W + x0) * (C / 4) + lane;
        const int i01 = (y0 * W + x1) * (C / 4) + lane;
        const int i10 = (y1 * W + x0) * (C / 4) + lane;
        const int i11 = (y1 * W + x1) * (C / 4) + lane;

        const f32x4 v00 = f4[i00];
        const f32x4 v01 = f4[i01];
        const f32x4 v10 = f4[i10];
        const f32x4 v11 = f4[i11];

        const f32x4 top = v00 + (v01 - v00) * wx;
        const f32x4 bot = v10 + (v11 - v10) * wx;
        f32x4 res = top + (bot - top) * wy;

        if (!valid) res = (f32x4)0.0f;

        // streaming store: output never re-read; keep feats L2-resident.
        __builtin_nontemporal_store(res, &o4[(size_t)b * CROP_HW * (C / 4)
                                             + (size_t)r * (C / 4) + lane]);
    }
}

extern "C" void kernel_launch(void* const* d_in, const int* in_sizes, int n_in,
                              void* d_out, int out_size, void* d_ws, size_t ws_size,
                              hipStream_t stream) {
    const float* feats   = (const float*)d_in[0];
    const float* boxes   = (const float*)d_in[1];
    const int*   box_ind = (const int*)d_in[2];
    float*       out     = (float*)d_out;

    const int n_boxes = in_sizes[1] / 4;

    int* order   = (int*)d_ws;            // n_boxes ints
    int* offsets = order + n_boxes;       // 9 ints

    bucket_kernel<<<1, 512, 0, stream>>>(box_ind, order, offsets, n_boxes);

    // 2048 blocks x 256 threads; 256 blocks (1024 waves) per image.
    crop_resize_xcd<<<2048, 256, 0, stream>>>(feats, boxes, order, offsets, out);
}

// Round 4
// 78.249 us; speedup vs baseline: 1.5351x; 1.0003x over previous
//
#include <hip/hip_runtime.h>

// crop_and_resize (RoIAlign-style bilinear), fp32, NHWC.
// feats: (8, 64, 64, 256) fp32 = 4 MiB/image; boxes: (4000,4); box_ind: (4000,)
// out:   (4000, 7, 7, 256) fp32
//
// XCD-locality: one image = 4 MiB = one XCD's L2. Kernel 1 buckets boxes by
// image (stable). Kernel 2 pins image i to blocks with blockIdx.x % 8 == i.
// R4 change: 2 cells per wave-iteration -> 8 corner loads in flight (MLP x2).

#define H 64
#define W 64
#define C 256
#define CROP_HW 49  // 7*7
#define NIMG 8

typedef float f32x4 __attribute__((ext_vector_type(4)));

// ---- kernel 1: stable bucket of box indices by image --------------------
__global__ __launch_bounds__(512) void bucket_kernel(
    const int* __restrict__ box_ind,
    int* __restrict__ order,     // [n] box ids grouped by image (stable)
    int* __restrict__ offsets,   // [9] bucket offsets
    int n)
{
    const int wave = threadIdx.x >> 6;   // 0..7 == image id
    const int lane = threadIdx.x & 63;
    __shared__ int counts[NIMG];

    int cnt = 0;
    for (int i = lane; i < n; i += 64)
        cnt += (box_ind[i] == wave);
    for (int off = 32; off; off >>= 1)
        cnt += __shfl_down(cnt, off);
    if (lane == 0) counts[wave] = cnt;
    __syncthreads();

    int start = 0;
    for (int i = 0; i < wave; ++i) start += counts[i];
    if (threadIdx.x == 0) {
        int acc = 0;
        for (int i = 0; i < NIMG; ++i) { offsets[i] = acc; acc += counts[i]; }
        offsets[NIMG] = acc;
    }

    int pos = start;
    for (int base = 0; base < n; base += 64) {
        const int i = base + lane;
        const bool m = (i < n) && (box_ind[i] == wave);
        const unsigned long long mask = __ballot(m);
        const int below = __popcll(mask & ((1ULL << lane) - 1ULL));
        if (m) order[pos + below] = i;
        pos += __popcll(mask);
    }
}

// ---- per-cell geometry ----------------------------------------------------
struct Cell {
    int i00, i01, i10, i11;   // float4-granular feats indices (within image)
    float wx, wy;
    bool valid;
    size_t oidx;              // float4-granular output index (without lane)
};

__device__ __forceinline__ Cell cell_info(
    int c, const int* __restrict__ order, const float* __restrict__ boxes,
    int start, int lane)
{
    Cell k;
    const int bi = c / CROP_HW;
    const int r  = c - bi * CROP_HW;
    const int iy = r / 7;
    const int ix = r - iy * 7;
    const int b  = order[start + bi];

    const float by1 = boxes[b * 4 + 0];
    const float bx1 = boxes[b * 4 + 1];
    const float by2 = boxes[b * 4 + 2];
    const float bx2 = boxes[b * 4 + 3];

    // reference order: step = (hi-lo)*(extent-1)/(n-1); s = lo*(extent-1)+i*step
    const float stepy = (by2 - by1) * 63.0f / 6.0f;
    const float stepx = (bx2 - bx1) * 63.0f / 6.0f;
    const float ys = by1 * 63.0f + (float)iy * stepy;
    const float xs = bx1 * 63.0f + (float)ix * stepx;

    const float y0f = floorf(ys);
    const float x0f = floorf(xs);
    k.wy = ys - y0f;
    k.wx = xs - x0f;

    const int y0 = min(max((int)y0f, 0), H - 1);
    const int y1 = min(y0 + 1, H - 1);
    const int x0 = min(max((int)x0f, 0), W - 1);
    const int x1 = min(x0 + 1, W - 1);

    k.valid = (ys >= 0.0f) && (ys <= (float)(H - 1)) &&
              (xs >= 0.0f) && (xs <= (float)(W - 1));

    k.i00 = (y0 * W + x0) * (C / 4) + lane;
    k.i01 = (y0 * W + x1) * (C / 4) + lane;
    k.i10 = (y1 * W + x0) * (C / 4) + lane;
    k.i11 = (y1 * W + x1) * (C / 4) + lane;

    k.oidx = (size_t)b * CROP_HW * (C / 4) + (size_t)r * (C / 4);
    return k;
}

__device__ __forceinline__ f32x4 lerp2(const f32x4& v00, const f32x4& v01,
                                       const f32x4& v10, const f32x4& v11,
                                       float wx, float wy, bool valid)
{
    const f32x4 top = v00 + (v01 - v00) * wx;
    const f32x4 bot = v10 + (v11 - v10) * wx;
    f32x4 res = top + (bot - top) * wy;
    if (!valid) res = (f32x4)0.0f;
    return res;
}

// ---- kernel 2: bilinear crop, image-partitioned by XCD, 2 cells/iter -----
__global__ __launch_bounds__(256) void crop_resize_xcd(
    const float* __restrict__ feats,
    const float* __restrict__ boxes,
    const int*   __restrict__ order,
    const int*   __restrict__ offsets,
    float*       __restrict__ out)
{
    const int img  = blockIdx.x & 7;     // block->XCD round-robin heuristic
    const int slot = blockIdx.x >> 3;
    const int lane = threadIdx.x & 63;
    const int wv   = threadIdx.x >> 6;   // 0..3

    const int start  = offsets[img];
    const int nb     = offsets[img + 1] - start;
    const int ncells = nb * CROP_HW;
    const int npairs = (ncells + 1) >> 1;
    const int wave_local = slot * 4 + wv;
    const int stride     = (gridDim.x >> 3) * 4;

    const f32x4* __restrict__ f4 = reinterpret_cast<const f32x4*>(feats)
                                   + (size_t)img * (H * W * (C / 4));
    f32x4* __restrict__ o4 = reinterpret_cast<f32x4*>(out);

    for (int p = wave_local; p < npairs; p += stride) {
        const int  c0    = p * 2;
        const bool haveB = (c0 + 1 < ncells);          // wave-uniform
        const int  c1    = haveB ? c0 + 1 : c0;        // duplicate loads if tail

        const Cell a = cell_info(c0, order, boxes, start, lane);
        const Cell bb = cell_info(c1, order, boxes, start, lane);

        // issue all 8 loads before any lerp (8-deep MLP per wave)
        const f32x4 a00 = f4[a.i00];
        const f32x4 a01 = f4[a.i01];
        const f32x4 a10 = f4[a.i10];
        const f32x4 a11 = f4[a.i11];
        const f32x4 b00 = f4[bb.i00];
        const f32x4 b01 = f4[bb.i01];
        const f32x4 b10 = f4[bb.i10];
        const f32x4 b11 = f4[bb.i11];

        const f32x4 resA = lerp2(a00, a01, a10, a11, a.wx, a.wy, a.valid);
        __builtin_nontemporal_store(resA, &o4[a.oidx + lane]);

        if (haveB) {
            const f32x4 resB = lerp2(b00, b01, b10, b11, bb.wx, bb.wy, bb.valid);
            __builtin_nontemporal_store(resB, &o4[bb.oidx + lane]);
        }
    }
}

extern "C" void kernel_launch(void* const* d_in, const int* in_sizes, int n_in,
                              void* d_out, int out_size, void* d_ws, size_t ws_size,
                              hipStream_t stream) {
    const float* feats   = (const float*)d_in[0];
    const float* boxes   = (const float*)d_in[1];
    const int*   box_ind = (const int*)d_in[2];
    float*       out     = (float*)d_out;

    const int n_boxes = in_sizes[1] / 4;

    int* order   = (int*)d_ws;            // n_boxes ints
    int* offsets = order + n_boxes;       // 9 ints

    bucket_kernel<<<1, 512, 0, stream>>>(box_ind, order, offsets, n_boxes);

    // 2048 blocks x 256 threads; 256 blocks (1024 waves) per image.
    crop_resize_xcd<<<2048, 256, 0, stream>>>(feats, boxes, order, offsets, out);
}